// Round 15
// baseline (187.088 us; speedup 1.0000x reference)
//
#include <hip/hip_runtime.h>

#define B_ 128
#define T_ 256
#define C_ 512
#define H_ 512
// softmax scale * log2(e):  (1/sqrt(512)) * 1.44269504
#define CSCALE 0.063763824f

typedef _Float16 f16x8 __attribute__((ext_vector_type(8)));
typedef _Float16 f16x4 __attribute__((ext_vector_type(4)));
typedef _Float16 f16x2 __attribute__((ext_vector_type(2)));
typedef float    f32x4 __attribute__((ext_vector_type(4)));
typedef unsigned int u32;
typedef u32 u32x4 __attribute__((ext_vector_type(4)));

// async global->LDS, 16B per lane; LDS dest must be wave-uniform base (+lane*16)
__device__ __forceinline__ void gld16(const void* gsrc, void* ldst) {
  __builtin_amdgcn_global_load_lds(
      (__attribute__((address_space(1))) void*)gsrc,
      (__attribute__((address_space(3))) void*)ldst, 16, 0, 0);
}

// ---------------------------------------------------------------- x convert
__global__ __launch_bounds__(256) void cvtx_kernel(
    const float4* __restrict__ x, f16x4* __restrict__ dst) {
  const int NX = (B_ * T_ * C_) / 4;  // 4,194,304
  int gid = blockIdx.x * 256 + threadIdx.x;
  int gsz = gridDim.x * 256;
  for (int i = gid; i < NX; i += gsz) {
    float4 f = x[i];
    f16x4 u = {(_Float16)f.x, (_Float16)f.y, (_Float16)f.z, (_Float16)f.w};
    dst[i] = u;
  }
}

// ---------------------------------------------------------------- W convert
__global__ __launch_bounds__(256) void cvtw_kernel(
    const float4* __restrict__ wq, const float4* __restrict__ wk,
    const float4* __restrict__ wv, f16x4* __restrict__ dst) {
  const int NW = (H_ * C_) / 4;  // 65,536
  int i = blockIdx.x * 256 + threadIdx.x;
  if (i >= 3 * NW) return;
  float4 f = (i < NW) ? wq[i] : (i < 2 * NW ? wk[i - NW] : wv[i - 2 * NW]);
  f16x4 u = {(_Float16)f.x, (_Float16)f.y, (_Float16)f.z, (_Float16)f.w};
  dst[i] = u;
}

// ---------------------------------------------------------------- QKV proj
// (FROZEN R5-exact -- structural 80 us at K=512 across 6 schedule variants.)
__global__ __launch_bounds__(256) void proj_kernel(
    const _Float16* __restrict__ xh, const _Float16* __restrict__ wh,
    _Float16* __restrict__ qh, _Float16* __restrict__ kh,
    _Float16* __restrict__ vth) {
  __shared__ _Float16 As[128 * 32];  // 8 KB, row-major [128][32]
  __shared__ _Float16 Bs[128 * 32];  // 8 KB

  const int tid  = threadIdx.x;
  const int lane = tid & 63;
  const int wave = tid >> 6;
  const int lr = lane & 15, lk = lane >> 4;
  const int m0 = blockIdx.x * 128;
  const int n0 = blockIdx.y * 128;
  const int z  = blockIdx.z;
  const _Float16* wz = wh + z * (H_ * C_);

  const int wm = (wave >> 1) * 64;
  const int wn = (wave & 1) * 64;

  f32x4 acc[4][4];
#pragma unroll
  for (int i = 0; i < 4; ++i)
#pragma unroll
    for (int j = 0; j < 4; ++j) acc[i][j] = {0.f, 0.f, 0.f, 0.f};

  const int srow = tid >> 2, scol = (tid & 3) * 8;
  const _Float16* aSrc = xh + (size_t)(m0 + srow) * C_ + scol;
  const _Float16* bSrc = wz + (size_t)(n0 + srow) * C_ + scol;

  for (int k0 = 0; k0 < C_; k0 += 32) {
    __syncthreads();
#pragma unroll
    for (int i = 0; i < 2; ++i) {
      gld16((const void*)(aSrc + i * 64 * C_ + k0), (void*)&As[i * 2048 + wave * 512]);
      gld16((const void*)(bSrc + i * 64 * C_ + k0), (void*)&Bs[i * 2048 + wave * 512]);
    }
    __syncthreads();

    f16x8 a[4], b[4];
#pragma unroll
    for (int mi = 0; mi < 4; ++mi)
      a[mi] = *(const f16x8*)&As[(wm + mi * 16 + lr) * 32 + lk * 8];
#pragma unroll
    for (int ni = 0; ni < 4; ++ni)
      b[ni] = *(const f16x8*)&Bs[(wn + ni * 16 + lr) * 32 + lk * 8];
#pragma unroll
    for (int mi = 0; mi < 4; ++mi)
#pragma unroll
      for (int ni = 0; ni < 4; ++ni)
        acc[mi][ni] = __builtin_amdgcn_mfma_f32_16x16x32_f16(a[mi], b[ni], acc[mi][ni], 0, 0, 0);
  }

  if (z < 2) {
    _Float16* out = (z == 0) ? qh : kh;
#pragma unroll
    for (int mi = 0; mi < 4; ++mi) {
      int mbase = m0 + wm + mi * 16 + lk * 4;
#pragma unroll
      for (int ni = 0; ni < 4; ++ni) {
        int n = n0 + wn + ni * 16 + lr;
#pragma unroll
        for (int r = 0; r < 4; ++r)
          out[(size_t)(mbase + r) * H_ + n] = (_Float16)acc[mi][ni][r];
      }
    }
  } else {
#pragma unroll
    for (int mi = 0; mi < 4; ++mi) {
      int mbase = m0 + wm + mi * 16 + lk * 4;
      int bb = mbase >> 8, tt = mbase & 255;
#pragma unroll
      for (int ni = 0; ni < 4; ++ni) {
        int n = n0 + wn + ni * 16 + lr;
        f16x4 u = {(_Float16)acc[mi][ni][0], (_Float16)acc[mi][ni][1],
                   (_Float16)acc[mi][ni][2], (_Float16)acc[mi][ni][3]};
        *(f16x4*)&vth[(size_t)bb * (H_ * T_) + (size_t)n * T_ + tt] = u;
      }
    }
  }
}

// ---------------------------------------------------------------- attention
// PAIR-WAVE FULL-S rewrite. Old structure: 16 MFMA per softmax + a 4-wave
// exchange/barrier per tile -> fixed serial cost dominates 4:1 (MfmaUtil 4%,
// floored ~78us across 7 pipelining variants). New: each wave owns 16 q-rows
// and computes the FULL S over H=512 (swapped 16x16x32, 32 QK MFMA/tile) ->
// softmax is wave-local, NO cross-wave exchange. Q in registers (64 VGPR,
// B-frag layout). K staged to LDS (shared by all 4 waves), XOR-swizzled
// (byte ^= (row&7)<<4) -> verified uniform 8 accesses/bank = b128 floor;
// ping-pong dbuf, stage(t+1) issued at tile start, ONE barrier/tile.
// Each wave does PV on an H-half (ot 64 VGPR); QK duplicated 2x across the
// h-half pair -- +50% FLOPs for zero sync. 48 MFMA per softmax (was 16).
// Both 16-row halves of a 32-q tile need the same kv extent -> uniform nkv.
// VGPR ~206 < 256 cap (256,2); LDS 64KB -> 2 blocks/CU.
__global__ __launch_bounds__(256, 2) void attn_kernel(
    const _Float16* __restrict__ qh, const _Float16* __restrict__ kh,
    const _Float16* __restrict__ vth, float* __restrict__ dout) {
  __shared__ _Float16 Kl[2][32 * 512];  // 64 KB, XOR-swizzled K[32kv][512h]

  const int tid  = threadIdx.x;
  const int lane = tid & 63;
  const int w    = tid >> 6;          // 0..3
  const int lr = lane & 15, lk = lane >> 4;
  const int qsub = w >> 1;            // 16-q half of the 32-q tile
  const int hh   = w & 1;             // H-half for PV/output
  const int flat = blockIdx.x;        // 0..1023
  const int xcd  = flat & 7;
  const int rest = flat >> 3;
  const int qb   = 7 - (rest & 7);    // long-first within each XCD stream
  const int g    = rest >> 3;         // 0..15
  const int b    = xcd + (g << 3);    // batch, pinned to XCD b%8
  const int q0   = qb * 32;
  const int nkv  = qb + 1;            // kv tiles of 32 (same for both halves)
  const int qg   = q0 + qsub * 16 + lr;  // this lane's q row (B-frag col)
  const int h0   = hh * 256;

  // Q in registers, B-frag layout: lane holds Q[qg][hs*32 + lk*8 + j]
  f16x8 qf[16];
  const _Float16* qp = qh + ((size_t)b * T_ + qg) * H_ + lk * 8;
#pragma unroll
  for (int hs = 0; hs < 16; ++hs) qf[hs] = *(const f16x8*)&qp[hs * 32];

  f32x4 ot[16];  // O^T H-half: [hsub] -> h = h0 + hsub*16 + lk*4 + r, col q
#pragma unroll
  for (int i = 0; i < 16; ++i) ot[i] = {0.f, 0.f, 0.f, 0.f};
  float m_ = -1e30f, l_ = 0.f;

  const _Float16* kbase = kh + (size_t)b * T_ * H_;
  const _Float16* vp = vth + ((size_t)b * H_ + h0 + lr) * T_ + lk * 8;
  const int swz = (lr & 7) << 3;  // f16-element XOR for K reads

  // stage K rows w*8..w*8+7: LDS linear dest; SOURCE pre-permuted so LDS
  // elem e of row kv holds global h = e ^ ((kv&7)<<3)  (G21 both-sides)
#define KSTAGE(BUF, KV0) do {                                                 \
    _Pragma("unroll") for (int i = 0; i < 8; ++i) {                            \
      int kv = w * 8 + i;                                                      \
      gld16((const void*)(kbase + ((size_t)((KV0) + kv)) * H_ +                \
                          8 * (lane ^ (kv & 7))),                              \
            (void*)&Kl[BUF][kv * 512]);                                        \
    }                                                                          \
  } while (0)

  KSTAGE(0, 0);
  __syncthreads();  // drains vmcnt(0): K(0) + qf landed

  for (int t = 0; t < nkv; ++t) {
    const int kv0 = t * 32;
    const int buf = t & 1;
    if (t + 1 < nkv) KSTAGE(buf ^ 1, kv0 + 32);  // flies under this tile

    // ---- QK^T full-H: S^T[32kv x 16q]; A = K from LDS, B = Q regs
    f32x4 s0 = {0.f, 0.f, 0.f, 0.f}, s1 = {0.f, 0.f, 0.f, 0.f};
#pragma unroll
    for (int hs = 0; hs < 16; ++hs) {
      int col = (hs * 32 + lk * 8) ^ swz;
      f16x8 a0 = *(const f16x8*)&Kl[buf][lr * 512 + col];
      f16x8 a1 = *(const f16x8*)&Kl[buf][(16 + lr) * 512 + col];
      s0 = __builtin_amdgcn_mfma_f32_16x16x32_f16(a0, qf[hs], s0, 0, 0, 0);
      s1 = __builtin_amdgcn_mfma_f32_16x16x32_f16(a1, qf[hs], s1, 0, 0, 0);
    }

    // ---- early-issue first half of V (lands during softmax+pack)
    f16x8 vf[8];
#pragma unroll
    for (int hsub = 0; hsub < 8; ++hsub)
      vf[hsub] = *(const f16x8*)&vp[(size_t)(hsub * 16) * T_ + kv0];

    // ---- causal mask + softmax (q = lane col; kv rows = lk*4+r, +16)
    float rm = -1e30f;
#pragma unroll
    for (int r = 0; r < 4; ++r) {
      int kva = kv0 + lk * 4 + r;
      float v0 = (kva > qg)      ? -1e30f : s0[r];
      float v1 = (kva + 16 > qg) ? -1e30f : s1[r];
      s0[r] = v0; s1[r] = v1;
      rm = fmaxf(rm, fmaxf(v0, v1));
    }
    rm = fmaxf(rm, __shfl_xor(rm, 16, 64));
    rm = fmaxf(rm, __shfl_xor(rm, 32, 64));

    // defer-max (T13)
    if (__any((int)(rm > m_ + 64.f))) {
      float mn = fmaxf(m_, rm);
      float al = __builtin_amdgcn_exp2f((m_ - mn) * CSCALE);
      m_ = mn; l_ *= al;
#pragma unroll
      for (int i = 0; i < 16; ++i)
#pragma unroll
        for (int e = 0; e < 4; ++e) ot[i][e] *= al;
    }
    float rs = 0.f;
#pragma unroll
    for (int r = 0; r < 4; ++r) {
      s0[r] = __builtin_amdgcn_exp2f((s0[r] - m_) * CSCALE);
      s1[r] = __builtin_amdgcn_exp2f((s1[r] - m_) * CSCALE);
      rs += s0[r] + s1[r];
    }
    rs += __shfl_xor(rs, 16, 64);
    rs += __shfl_xor(rs, 32, 64);
    l_ += rs;

    // ---- P^T -> PV B-frag: lane needs P[kv=lk*8+j][q=lr].
    // kv = X*16 + lk'*4 + (j&3), X = lk>>1, lk' = 2*(lk&1) + (j>>2)
    // -> 4 cvt_pk pairs + 8 dynamic shfl + 4 selects.
    f16x8 pb;
    {
      f16x2 p0 = {(_Float16)s0[0], (_Float16)s0[1]};
      f16x2 p1 = {(_Float16)s0[2], (_Float16)s0[3]};
      f16x2 p2 = {(_Float16)s1[0], (_Float16)s1[1]};
      f16x2 p3 = {(_Float16)s1[2], (_Float16)s1[3]};
      u32 u0 = __builtin_bit_cast(u32, p0), u1 = __builtin_bit_cast(u32, p1);
      u32 u2 = __builtin_bit_cast(u32, p2), u3 = __builtin_bit_cast(u32, p3);
      int srcA = ((lk & 1) << 5) | lr;   // owner lk' = 2*(lk&1)
      int srcB = srcA + 16;              // owner lk' = 2*(lk&1)+1
      u32 a0 = (u32)__shfl((int)u0, srcA, 64);
      u32 a1 = (u32)__shfl((int)u1, srcA, 64);
      u32 a2 = (u32)__shfl((int)u2, srcA, 64);
      u32 a3 = (u32)__shfl((int)u3, srcA, 64);
      u32 b0 = (u32)__shfl((int)u0, srcB, 64);
      u32 b1 = (u32)__shfl((int)u1, srcB, 64);
      u32 b2 = (u32)__shfl((int)u2, srcB, 64);
      u32 b3 = (u32)__shfl((int)u3, srcB, 64);
      bool X = (lk >> 1) & 1;            // subtile select
      u32x4 tt = { X ? a2 : a0, X ? a3 : a1, X ? b2 : b0, X ? b3 : b1 };
      pb = __builtin_bit_cast(f16x8, tt);
    }

    // ---- PV on H-half: O^T[256h x 16q] += V^T[h x 32kv] * P^T
    __builtin_amdgcn_s_setprio(1);
#pragma unroll
    for (int hsub = 0; hsub < 8; ++hsub)
      ot[hsub] = __builtin_amdgcn_mfma_f32_16x16x32_f16(vf[hsub], pb, ot[hsub], 0, 0, 0);
#pragma unroll
    for (int hsub = 8; hsub < 16; ++hsub) {
      f16x8 va = *(const f16x8*)&vp[(size_t)(hsub * 16) * T_ + kv0];
      ot[hsub] = __builtin_amdgcn_mfma_f32_16x16x32_f16(va, pb, ot[hsub], 0, 0, 0);
    }
    __builtin_amdgcn_s_setprio(0);

    __syncthreads();  // drains stage(t+1) (vmcnt 0) + guards buf reuse
  }

  // ---- normalize + store fp32 (lane's q row, wave's 256 H-cols)
  float li = 1.0f / l_;
  float* op = dout + ((size_t)b * T_ + qg) * H_ + h0 + lk * 4;
#pragma unroll
  for (int hsub = 0; hsub < 16; ++hsub) {
    f32x4 v4 = {ot[hsub][0] * li, ot[hsub][1] * li,
                ot[hsub][2] * li, ot[hsub][3] * li};
    *(f32x4*)&op[hsub * 16] = v4;
  }
}

// ---------------------------------------------------------------- launch
extern "C" void kernel_launch(void* const* d_in, const int* in_sizes, int n_in,
                              void* d_out, int out_size, void* d_ws, size_t ws_size,
                              hipStream_t stream) {
  const size_t NXE = (size_t)B_ * T_ * C_;   // 16,777,216
  const size_t NWE = (size_t)3 * H_ * C_;    // 786,432
  const size_t NQE = (size_t)B_ * T_ * H_;   // 16,777,216
  const size_t need = (NXE + NWE + 3 * NQE) * sizeof(_Float16);  // 135,790,592 B
  if (ws_size < need) return;  // loud failure (absmax = max|ref|) -> ws too small

  const float* x  = (const float*)d_in[0];
  const float* wq = (const float*)d_in[1];
  const float* wk = (const float*)d_in[2];
  const float* wv = (const float*)d_in[3];

  _Float16* xh  = (_Float16*)d_ws;
  _Float16* whh = xh + NXE;
  _Float16* qh  = whh + NWE;
  _Float16* kh  = qh + NQE;
  _Float16* vth = kh + NQE;

  cvtx_kernel<<<2048, 256, 0, stream>>>((const float4*)x, (f16x4*)xh);
  cvtw_kernel<<<768, 256, 0, stream>>>((const float4*)wq, (const float4*)wk,
                                       (const float4*)wv, (f16x4*)whh);
  proj_kernel<<<dim3(256, 4, 3), dim3(256), 0, stream>>>(xh, whh, qh, kh, vth);
  attn_kernel<<<1024, 256, 0, stream>>>(qh, kh, vth, (float*)d_out);
}

// Round 16
// 161.991 us; speedup vs baseline: 1.1549x; 1.1549x over previous
//
#include <hip/hip_runtime.h>

#define B_ 128
#define T_ 256
#define C_ 512
#define H_ 512
// softmax scale * log2(e):  (1/sqrt(512)) * 1.44269504
#define CSCALE 0.063763824f

typedef _Float16 f16x8 __attribute__((ext_vector_type(8)));
typedef _Float16 f16x4 __attribute__((ext_vector_type(4)));
typedef float    f32x4 __attribute__((ext_vector_type(4)));

// async global->LDS, 16B per lane; LDS dest must be wave-uniform base (+lane*16)
__device__ __forceinline__ void gld16(const void* gsrc, void* ldst) {
  __builtin_amdgcn_global_load_lds(
      (__attribute__((address_space(1))) void*)gsrc,
      (__attribute__((address_space(3))) void*)ldst, 16, 0, 0);
}

// ---------------------------------------------------------------- x convert
__global__ __launch_bounds__(256) void cvtx_kernel(
    const float4* __restrict__ x, f16x4* __restrict__ dst) {
  const int NX = (B_ * T_ * C_) / 4;  // 4,194,304
  int gid = blockIdx.x * 256 + threadIdx.x;
  int gsz = gridDim.x * 256;
  for (int i = gid; i < NX; i += gsz) {
    float4 f = x[i];
    f16x4 u = {(_Float16)f.x, (_Float16)f.y, (_Float16)f.z, (_Float16)f.w};
    dst[i] = u;
  }
}

// ---------------------------------------------------------------- W convert
__global__ __launch_bounds__(256) void cvtw_kernel(
    const float4* __restrict__ wq, const float4* __restrict__ wk,
    const float4* __restrict__ wv, f16x4* __restrict__ dst) {
  const int NW = (H_ * C_) / 4;  // 65,536
  int i = blockIdx.x * 256 + threadIdx.x;
  if (i >= 3 * NW) return;
  float4 f = (i < NW) ? wq[i] : (i < 2 * NW ? wk[i - NW] : wv[i - 2 * NW]);
  f16x4 u = {(_Float16)f.x, (_Float16)f.y, (_Float16)f.z, (_Float16)f.w};
  dst[i] = u;
}

// ---------------------------------------------------------------- QKV proj
// (FROZEN R5-exact -- structural 80 us at K=512 across 6 schedule variants.)
__global__ __launch_bounds__(256) void proj_kernel(
    const _Float16* __restrict__ xh, const _Float16* __restrict__ wh,
    _Float16* __restrict__ qh, _Float16* __restrict__ kh,
    _Float16* __restrict__ vth) {
  __shared__ _Float16 As[128 * 32];  // 8 KB, row-major [128][32]
  __shared__ _Float16 Bs[128 * 32];  // 8 KB

  const int tid  = threadIdx.x;
  const int lane = tid & 63;
  const int wave = tid >> 6;
  const int lr = lane & 15, lk = lane >> 4;
  const int m0 = blockIdx.x * 128;
  const int n0 = blockIdx.y * 128;
  const int z  = blockIdx.z;
  const _Float16* wz = wh + z * (H_ * C_);

  const int wm = (wave >> 1) * 64;
  const int wn = (wave & 1) * 64;

  f32x4 acc[4][4];
#pragma unroll
  for (int i = 0; i < 4; ++i)
#pragma unroll
    for (int j = 0; j < 4; ++j) acc[i][j] = {0.f, 0.f, 0.f, 0.f};

  const int srow = tid >> 2, scol = (tid & 3) * 8;
  const _Float16* aSrc = xh + (size_t)(m0 + srow) * C_ + scol;
  const _Float16* bSrc = wz + (size_t)(n0 + srow) * C_ + scol;

  for (int k0 = 0; k0 < C_; k0 += 32) {
    __syncthreads();
#pragma unroll
    for (int i = 0; i < 2; ++i) {
      gld16((const void*)(aSrc + i * 64 * C_ + k0), (void*)&As[i * 2048 + wave * 512]);
      gld16((const void*)(bSrc + i * 64 * C_ + k0), (void*)&Bs[i * 2048 + wave * 512]);
    }
    __syncthreads();

    f16x8 a[4], b[4];
#pragma unroll
    for (int mi = 0; mi < 4; ++mi)
      a[mi] = *(const f16x8*)&As[(wm + mi * 16 + lr) * 32 + lk * 8];
#pragma unroll
    for (int ni = 0; ni < 4; ++ni)
      b[ni] = *(const f16x8*)&Bs[(wn + ni * 16 + lr) * 32 + lk * 8];
#pragma unroll
    for (int mi = 0; mi < 4; ++mi)
#pragma unroll
      for (int ni = 0; ni < 4; ++ni)
        acc[mi][ni] = __builtin_amdgcn_mfma_f32_16x16x32_f16(a[mi], b[ni], acc[mi][ni], 0, 0, 0);
  }

  if (z < 2) {
    _Float16* out = (z == 0) ? qh : kh;
#pragma unroll
    for (int mi = 0; mi < 4; ++mi) {
      int mbase = m0 + wm + mi * 16 + lk * 4;
#pragma unroll
      for (int ni = 0; ni < 4; ++ni) {
        int n = n0 + wn + ni * 16 + lr;
#pragma unroll
        for (int r = 0; r < 4; ++r)
          out[(size_t)(mbase + r) * H_ + n] = (_Float16)acc[mi][ni][r];
      }
    }
  } else {
#pragma unroll
    for (int mi = 0; mi < 4; ++mi) {
      int mbase = m0 + wm + mi * 16 + lk * 4;
      int bb = mbase >> 8, tt = mbase & 255;
#pragma unroll
      for (int ni = 0; ni < 4; ++ni) {
        int n = n0 + wn + ni * 16 + lr;
        f16x4 u = {(_Float16)acc[mi][ni][0], (_Float16)acc[mi][ni][1],
                   (_Float16)acc[mi][ni][2], (_Float16)acc[mi][ni][3]};
        *(f16x4*)&vth[(size_t)bb * (H_ * T_) + (size_t)n * T_ + tt] = u;
      }
    }
  }
}

// ---------------------------------------------------------------- QK^T GEMM
// UNFUSED ATTENTION step 1/3. T=256 -> S is only 16.8 MB f16 (fits the dead
// xh region), so flash fusion is unnecessary; 8 fused variants floored at
// 78-137us (chain-bound, all pipes idle). As a batched m97 GEMM instead:
// S[b][i][j] = q[b,i,:].k[b,j,:]  (raw scores, scale folded into softmax).
// Causal tile-skip: per batch only tiles (0,0),(1,0),(1,1) -> 384 blocks.
__global__ __launch_bounds__(256) void qk_kernel(
    const _Float16* __restrict__ qh, const _Float16* __restrict__ kh,
    _Float16* __restrict__ S) {
  __shared__ _Float16 As[128 * 32];
  __shared__ _Float16 Bs[128 * 32];

  const int tid  = threadIdx.x;
  const int lane = tid & 63;
  const int wave = tid >> 6;
  const int lr = lane & 15, lk = lane >> 4;
  const int tx = blockIdx.x;          // 0..2 -> (ti,tj) in {(0,0),(1,0),(1,1)}
  const int ti = (tx + 1) >> 1, tj = tx >> 1;
  const int b  = blockIdx.y;
  const int m0 = ti * 128, n0 = tj * 128;

  const int wm = (wave >> 1) * 64;
  const int wn = (wave & 1) * 64;

  f32x4 acc[4][4];
#pragma unroll
  for (int i = 0; i < 4; ++i)
#pragma unroll
    for (int j = 0; j < 4; ++j) acc[i][j] = {0.f, 0.f, 0.f, 0.f};

  const int srow = tid >> 2, scol = (tid & 3) * 8;
  const _Float16* aSrc = qh + ((size_t)b * T_ + m0 + srow) * H_ + scol;
  const _Float16* bSrc = kh + ((size_t)b * T_ + n0 + srow) * H_ + scol;

  for (int k0 = 0; k0 < H_; k0 += 32) {
    __syncthreads();
#pragma unroll
    for (int i = 0; i < 2; ++i) {
      gld16((const void*)(aSrc + i * 64 * H_ + k0), (void*)&As[i * 2048 + wave * 512]);
      gld16((const void*)(bSrc + i * 64 * H_ + k0), (void*)&Bs[i * 2048 + wave * 512]);
    }
    __syncthreads();

    f16x8 a[4], b4[4];
#pragma unroll
    for (int mi = 0; mi < 4; ++mi)
      a[mi] = *(const f16x8*)&As[(wm + mi * 16 + lr) * 32 + lk * 8];
#pragma unroll
    for (int ni = 0; ni < 4; ++ni)
      b4[ni] = *(const f16x8*)&Bs[(wn + ni * 16 + lr) * 32 + lk * 8];
#pragma unroll
    for (int mi = 0; mi < 4; ++mi)
#pragma unroll
      for (int ni = 0; ni < 4; ++ni)
        acc[mi][ni] = __builtin_amdgcn_mfma_f32_16x16x32_f16(a[mi], b4[ni], acc[mi][ni], 0, 0, 0);
  }

  // S row-major [T][T] per batch; D layout: col=lane&15, row=(lane>>4)*4+r
  _Float16* sb = S + (size_t)b * T_ * T_;
#pragma unroll
  for (int mi = 0; mi < 4; ++mi) {
    int mbase = m0 + wm + mi * 16 + lk * 4;
#pragma unroll
    for (int ni = 0; ni < 4; ++ni) {
      int n = n0 + wn + ni * 16 + lr;
#pragma unroll
      for (int r = 0; r < 4; ++r)
        sb[(size_t)(mbase + r) * T_ + n] = (_Float16)acc[mi][ni][r];
    }
  }
}

// ---------------------------------------------------------------- softmax
// UNFUSED step 2/3: in-place causal row softmax on S. One wave per row;
// 64 lanes x f16x4 = the full 256-col row, coalesced (512B/wave). Mask
// j>i BEFORE use (upper-right S tile is never written -- masked garbage).
__global__ __launch_bounds__(256) void sm_kernel(_Float16* __restrict__ S) {
  const int tid  = threadIdx.x;
  const int lane = tid & 63;
  const int wave = tid >> 6;
  const int R = blockIdx.x * 4 + wave;   // 0..32767
  const int b = R >> 8, i = R & 255;

  _Float16* row = S + ((size_t)b * T_ + i) * T_ + lane * 4;
  f16x4 v4 = *(const f16x4*)row;
  float v[4];
  float m = -1e30f;
#pragma unroll
  for (int e = 0; e < 4; ++e) {
    int j = lane * 4 + e;
    v[e] = (j > i) ? -1e30f : (float)v4[e];
    m = fmaxf(m, v[e]);
  }
#pragma unroll
  for (int off = 1; off < 64; off <<= 1) m = fmaxf(m, __shfl_xor(m, off, 64));
  float s = 0.f;
#pragma unroll
  for (int e = 0; e < 4; ++e) {
    v[e] = (v[e] <= -1e30f) ? 0.f : __builtin_amdgcn_exp2f((v[e] - m) * CSCALE);
    s += v[e];
  }
#pragma unroll
  for (int off = 1; off < 64; off <<= 1) s += __shfl_xor(s, off, 64);
  float li = 1.0f / s;
  f16x4 o = {(_Float16)(v[0] * li), (_Float16)(v[1] * li),
             (_Float16)(v[2] * li), (_Float16)(v[3] * li)};
  *(f16x4*)row = o;
}

// ---------------------------------------------------------------- PV GEMM
// UNFUSED step 3/3: out[b,q,h] = sum_k P[b,q,k] * V[b,k,h]; B-operand =
// vth rows (V^T, already K-major). m97 structure, K = (ti+1)*128 (causal:
// P[q<128, k>=128] == 0, skip). Grid (2 ti, 4 th, 128 b) = 1024 blocks.
__global__ __launch_bounds__(256) void pv_kernel(
    const _Float16* __restrict__ P, const _Float16* __restrict__ vth,
    float* __restrict__ dout) {
  __shared__ _Float16 As[128 * 32];
  __shared__ _Float16 Bs[128 * 32];

  const int tid  = threadIdx.x;
  const int lane = tid & 63;
  const int wave = tid >> 6;
  const int lr = lane & 15, lk = lane >> 4;
  const int ti = blockIdx.x;          // q tile
  const int m0 = ti * 128;
  const int n0 = blockIdx.y * 128;    // h tile
  const int b  = blockIdx.z;
  const int kmax = (ti + 1) * 128;    // causal K extent

  const int wm = (wave >> 1) * 64;
  const int wn = (wave & 1) * 64;

  f32x4 acc[4][4];
#pragma unroll
  for (int i = 0; i < 4; ++i)
#pragma unroll
    for (int j = 0; j < 4; ++j) acc[i][j] = {0.f, 0.f, 0.f, 0.f};

  const int srow = tid >> 2, scol = (tid & 3) * 8;
  const _Float16* aSrc = P + ((size_t)b * T_ + m0 + srow) * T_ + scol;
  const _Float16* bSrc = vth + ((size_t)b * H_ + n0 + srow) * T_ + scol;

  for (int k0 = 0; k0 < kmax; k0 += 32) {
    __syncthreads();
#pragma unroll
    for (int i = 0; i < 2; ++i) {
      gld16((const void*)(aSrc + i * 64 * T_ + k0), (void*)&As[i * 2048 + wave * 512]);
      gld16((const void*)(bSrc + i * 64 * T_ + k0), (void*)&Bs[i * 2048 + wave * 512]);
    }
    __syncthreads();

    f16x8 a[4], b4[4];
#pragma unroll
    for (int mi = 0; mi < 4; ++mi)
      a[mi] = *(const f16x8*)&As[(wm + mi * 16 + lr) * 32 + lk * 8];
#pragma unroll
    for (int ni = 0; ni < 4; ++ni)
      b4[ni] = *(const f16x8*)&Bs[(wn + ni * 16 + lr) * 32 + lk * 8];
#pragma unroll
    for (int mi = 0; mi < 4; ++mi)
#pragma unroll
      for (int ni = 0; ni < 4; ++ni)
        acc[mi][ni] = __builtin_amdgcn_mfma_f32_16x16x32_f16(a[mi], b4[ni], acc[mi][ni], 0, 0, 0);
  }

  // dout f32 [b*T + q][h]
  float* ob = dout + (size_t)b * T_ * H_;
#pragma unroll
  for (int mi = 0; mi < 4; ++mi) {
    int mbase = m0 + wm + mi * 16 + lk * 4;
#pragma unroll
    for (int ni = 0; ni < 4; ++ni) {
      int n = n0 + wn + ni * 16 + lr;
#pragma unroll
      for (int r = 0; r < 4; ++r)
        ob[(size_t)(mbase + r) * H_ + n] = acc[mi][ni][r];
    }
  }
}

// ---------------------------------------------------------------- launch
extern "C" void kernel_launch(void* const* d_in, const int* in_sizes, int n_in,
                              void* d_out, int out_size, void* d_ws, size_t ws_size,
                              hipStream_t stream) {
  const size_t NXE = (size_t)B_ * T_ * C_;   // 16,777,216 (xh; reused as S)
  const size_t NWE = (size_t)3 * H_ * C_;    // 786,432
  const size_t NQE = (size_t)B_ * T_ * H_;   // 16,777,216
  const size_t need = (NXE + NWE + 3 * NQE) * sizeof(_Float16);  // 135,790,592 B
  if (ws_size < need) return;  // loud failure (absmax = max|ref|) -> ws too small

  const float* x  = (const float*)d_in[0];
  const float* wq = (const float*)d_in[1];
  const float* wk = (const float*)d_in[2];
  const float* wv = (const float*)d_in[3];

  _Float16* xh  = (_Float16*)d_ws;   // 32 MB; dead after proj -> S aliases it
  _Float16* whh = xh + NXE;
  _Float16* qh  = whh + NWE;
  _Float16* kh  = qh + NQE;
  _Float16* vth = kh + NQE;
  _Float16* S   = xh;                // 16.8 MB (B*T*T f16) <= 32 MB region

  cvtx_kernel<<<2048, 256, 0, stream>>>((const float4*)x, (f16x4*)xh);
  cvtw_kernel<<<768, 256, 0, stream>>>((const float4*)wq, (const float4*)wk,
                                       (const float4*)wv, (f16x4*)whh);
  proj_kernel<<<dim3(256, 4, 3), dim3(256), 0, stream>>>(xh, whh, qh, kh, vth);
  qk_kernel<<<dim3(3, 128), dim3(256), 0, stream>>>(qh, kh, S);
  sm_kernel<<<8192, 256, 0, stream>>>(S);
  pv_kernel<<<dim3(2, 4, 128), dim3(256), 0, stream>>>(S, vth, (float*)d_out);
}